// Round 5
// baseline (354.360 us; speedup 1.0000x reference)
//
#include <hip/hip_runtime.h>

// Problem constants
#define BN   8
#define CC   256
#define HH   64
#define WW   64
#define GG   8
#define CG   32
#define KKK  9
#define OO   256
#define HW   (HH*WW)
#define NPAD 256
#define NOUT 216

typedef __attribute__((ext_vector_type(8))) _Float16 half8;
typedef __attribute__((ext_vector_type(4))) _Float16 half4;
typedef __attribute__((ext_vector_type(4))) float f32x4;

union U4H8 { uint4 u; half8 h; };
union U2H4 { uint2 u; half4 h; };

// ---------------------------------------------------------------------------
// K0a: repack w_out [O][C][3][3] -> wt3 f16 [g*9+kk][o 256][cg 32]
// ---------------------------------------------------------------------------
__global__ void repack_w(const float* __restrict__ w_out, _Float16* __restrict__ wt3) {
    int idx = blockIdx.x * 256 + threadIdx.x;
    if (idx >= GG * KKK * CG * OO) return;
    int cg = idx & 31;
    int o  = (idx >> 5) & 255;
    int s  = idx >> 13;
    int kk = s % 9;
    int g  = s / 9;
    wt3[idx] = (_Float16)w_out[o * 2304 + (g * 32 + cg) * 9 + kk];
}

// ---------------------------------------------------------------------------
// K0b: repack conv weights -> wt_conv f16 [tap][oc 256 padded][c 256]; bias[224]
// ---------------------------------------------------------------------------
__global__ void repack_conv(const float* __restrict__ w_off, const float* __restrict__ b_off,
                            const float* __restrict__ w_attn, const float* __restrict__ b_attn,
                            _Float16* __restrict__ wt_conv, float* __restrict__ bias_c) {
    int idx = blockIdx.x * 256 + threadIdx.x;
    if (idx >= 9 * NPAD * 256) return;
    int c = idx & 255;
    int r = idx >> 8;
    int n = r & 255;
    int tap = r >> 8;
    float v = 0.f;
    if (n < 144)      v = w_off[(n * 256 + c) * 9 + tap];
    else if (n < 216) v = w_attn[((n - 144) * 256 + c) * 9 + tap];
    wt_conv[(tap * NPAD + n) * 256 + c] = (_Float16)v;
    if (idx < 224) {
        float bv = 0.f;
        if (idx < 144)      bv = b_off[idx];
        else if (idx < 216) bv = b_attn[idx - 144];
        bias_c[idx] = bv;
    }
}

// ---------------------------------------------------------------------------
// K0c: repack x f32 NCHW -> x_h f16 NHWC [b][y][x][c]
// ---------------------------------------------------------------------------
__global__ __launch_bounds__(256) void repack_x(const float* __restrict__ x,
                                                _Float16* __restrict__ x_h) {
    __shared__ _Float16 T[64][264];
    const int bid = blockIdx.x;
    const int b = bid & 7, h = bid >> 3;
    const int t = threadIdx.x;   // = channel
    const float* src = x + (((long)(b * 256 + t)) << 12) + h * 64;
    #pragma unroll
    for (int i = 0; i < 16; ++i) {
        float4 f = ((const float4*)src)[i];
        T[i * 4 + 0][t] = (_Float16)f.x;
        T[i * 4 + 1][t] = (_Float16)f.y;
        T[i * 4 + 2][t] = (_Float16)f.z;
        T[i * 4 + 3][t] = (_Float16)f.w;
    }
    __syncthreads();
    _Float16* dst = x_h + (((long)(b * 4096 + h * 64)) << 8);
    #pragma unroll
    for (int it = 0; it < 8; ++it) {
        int idx = it * 256 + t;
        int px = idx >> 5, ch = idx & 31;
        uint4 v = *(const uint4*)&T[px][ch * 8];
        *(uint4*)(dst + px * 256 + ch * 8) = v;
    }
}

// ---------------------------------------------------------------------------
// K1: implicit-GEMM conv via f16 MFMA, M-split.
// Grid 1024 = (b, h, mh); block = 256 thr (4 N-waves).
// M = 32 px (half row), N = 256 (padded), full K.
// 72 stages (tap x 32-ch chunk), BK=32 -> 8 MFMA/wave/stage.
// A double-buffered in LDS ([40] stride); staging 8 thr/px x uint2.
// B register-direct from L2 one stage ahead; ONE __syncthreads per stage.
// 4 blocks/CU -> 4 independent barrier domains per SIMD.
// ---------------------------------------------------------------------------
__global__ __launch_bounds__(256, 4) void conv_mfma(
    const _Float16* __restrict__ x_h, const _Float16* __restrict__ wt_conv,
    const float* __restrict__ bias_c, float* __restrict__ conv_buf) {
    __shared__ _Float16 Ald[2][32][40];   // 5,120 B

    const int bid = blockIdx.x;
    const int b = bid & 7, h = (bid >> 3) & 63, mh = bid >> 9;
    const int t = threadIdx.x;
    const int lane = t & 63;
    const int wg = t >> 6;          // N quarter: oc wg*64 ..
    const int px2 = t >> 3;         // 0..31 local pixel
    const int pt = t & 7;           // 4-half slice within 32 ch

    f32x4 acc[2][4];
    #pragma unroll
    for (int i = 0; i < 2; ++i)
        #pragma unroll
        for (int j = 0; j < 4; ++j) acc[i][j] = (f32x4){0.f, 0.f, 0.f, 0.f};

    const _Float16* xb = x_h + ((long)b << 20) + pt * 4;
    const _Float16* wbase = wt_conv + (long)(wg * 64 + (lane & 15)) * 256
                            + (lane >> 4) * 8;

    uint2 aR; bool vA;
    uint4 bq0, bq1, bq2, bq3;

    // ---- prologue: A(0) -> buf0, A(1) -> regs, B(0) -> regs ----
    {
        // stage 0: tap 0 (y=h-1, x=X-1), chunk 0
        int y = h - 1, xc = mh * 32 + px2 - 1;
        bool v0 = ((unsigned)y < 64u) && ((unsigned)xc < 64u);
        int yc = min(max(y, 0), 63), xcc = min(max(xc, 0), 63);
        uint2 a0 = *(const uint2*)(xb + ((long)(yc * 64 + xcc)) * 256);
        uint2 z = make_uint2(0u, 0u);
        *(uint2*)&Ald[0][px2][pt * 4] = v0 ? a0 : z;
    }
    {
        // stage 1: tap 0, chunk 1
        int y = h - 1, xc = mh * 32 + px2 - 1;
        vA = ((unsigned)y < 64u) && ((unsigned)xc < 64u);
        int yc = min(max(y, 0), 63), xcc = min(max(xc, 0), 63);
        aR = *(const uint2*)(xb + ((long)(yc * 64 + xcc)) * 256 + 32);
    }
    {
        bq0 = *(const uint4*)(wbase);
        bq1 = *(const uint4*)(wbase + 4096);
        bq2 = *(const uint4*)(wbase + 8192);
        bq3 = *(const uint4*)(wbase + 12288);
    }
    __syncthreads();

    for (int s = 0; s < 72; ++s) {
        // (1) LDS write A(s+1) from prefetched regs (other buffer)
        if (s < 71) {
            uint2 z = make_uint2(0u, 0u);
            *(uint2*)&Ald[(s + 1) & 1][px2][pt * 4] = vA ? aR : z;
        }
        // (2) issue A(s+2)
        if (s < 70) {
            int sn = s + 2;
            int tap = sn >> 3, cc = sn & 7;
            int y = h + tap / 3 - 1, xc = mh * 32 + px2 + tap % 3 - 1;
            vA = ((unsigned)y < 64u) && ((unsigned)xc < 64u);
            int yc = min(max(y, 0), 63), xcc = min(max(xc, 0), 63);
            aR = *(const uint2*)(xb + ((long)(yc * 64 + xcc)) * 256 + cc * 32);
        }
        // (3) MFMA(s): 2 M x 4 N from LDS buf[s&1] x B(s) regs
        {
            const int k0 = (lane >> 4) * 8;
            U4H8 b0, b1, b2, b3; b0.u = bq0; b1.u = bq1; b2.u = bq2; b3.u = bq3;
            #pragma unroll
            for (int mi = 0; mi < 2; ++mi) {
                half8 a = *(const half8*)&Ald[s & 1][mi * 16 + (lane & 15)][k0];
                acc[mi][0] = __builtin_amdgcn_mfma_f32_16x16x32_f16(a, b0.h, acc[mi][0], 0, 0, 0);
                acc[mi][1] = __builtin_amdgcn_mfma_f32_16x16x32_f16(a, b1.h, acc[mi][1], 0, 0, 0);
                acc[mi][2] = __builtin_amdgcn_mfma_f32_16x16x32_f16(a, b2.h, acc[mi][2], 0, 0, 0);
                acc[mi][3] = __builtin_amdgcn_mfma_f32_16x16x32_f16(a, b3.h, acc[mi][3], 0, 0, 0);
            }
        }
        // (4) issue B(s+1)
        if (s < 71) {
            int sn = s + 1;
            const _Float16* wp = wbase + (long)(sn >> 3) * 65536 + (sn & 7) * 32;
            bq0 = *(const uint4*)(wp);
            bq1 = *(const uint4*)(wp + 4096);
            bq2 = *(const uint4*)(wp + 8192);
            bq3 = *(const uint4*)(wp + 12288);
        }
        // (5) barrier
        __syncthreads();
    }

    // ---- epilogue ----
    const int colb = (lane >> 4) * 4;
    #pragma unroll
    for (int mi = 0; mi < 2; ++mi) {
        int px0 = mh * 32 + mi * 16 + colb;
        #pragma unroll
        for (int j = 0; j < 4; ++j) {
            int oc = wg * 64 + j * 16 + (lane & 15);
            if (oc < NOUT) {
                float bb = bias_c[oc];
                float4 v = make_float4(acc[mi][j][0] + bb, acc[mi][j][1] + bb,
                                       acc[mi][j][2] + bb, acc[mi][j][3] + bb);
                *(float4*)&conv_buf[((long)b * NOUT + oc) * HW + h * WW + px0] = v;
            }
        }
    }
}

// ---------------------------------------------------------------------------
// coords without attn: masked bilinear weights + clamped corner indices
// ---------------------------------------------------------------------------
__device__ __forceinline__ void calc_coords(int h, int pxg, int ki, int kj,
    float dy, float dx,
    int& i00, int& i01, int& i10, int& i11,
    float& u00, float& u01, float& u10, float& u11) {
    float py  = (float)(h - 1 + ki) + dy;
    float pxf = (float)(pxg - 1 + kj) + dx;
    float y0f = floorf(py), x0f = floorf(pxf);
    int y0 = (int)y0f, x0 = (int)x0f;
    float wy1 = py - y0f, wx1 = pxf - x0f;
    float wy0 = 1.f - wy1, wx0 = 1.f - wx1;
    int y1 = y0 + 1, x1 = x0 + 1;
    float m00 = (((unsigned)y0 < 64u) && ((unsigned)x0 < 64u)) ? 1.f : 0.f;
    float m01 = (((unsigned)y0 < 64u) && ((unsigned)x1 < 64u)) ? 1.f : 0.f;
    float m10 = (((unsigned)y1 < 64u) && ((unsigned)x0 < 64u)) ? 1.f : 0.f;
    float m11 = (((unsigned)y1 < 64u) && ((unsigned)x1 < 64u)) ? 1.f : 0.f;
    int cy0 = min(max(y0, 0), 63), cy1 = min(max(y1, 0), 63);
    int cx0 = min(max(x0, 0), 63), cx1 = min(max(x1, 0), 63);
    u00 = wy0 * wx0 * m00; u01 = wy0 * wx1 * m01;
    u10 = wy1 * wx0 * m10; u11 = wy1 * wx1 * m11;
    i00 = cy0 * 64 + cx0; i01 = cy0 * 64 + cx1;
    i10 = cy1 * 64 + cx0; i11 = cy1 * 64 + cx1;
}

// ---------------------------------------------------------------------------
// K3: fused softmax + bilinear sampling + modulation + MFMA contraction.
// Grid 1024 = (b, h, mh); block = 256 thr (4 N-waves).
// M = 32 px, N = 256, full K (72 (g,kk) stages, BK=32).
// Gather/blend: 8 thr/px, uint2 per corner (4-half channel slice).
// A double-buffered; gathers/B prefetched one stage ahead; ONE barrier/stage.
// ---------------------------------------------------------------------------
__global__ __launch_bounds__(256, 4) void sample_gemm_mfma(
    const _Float16* __restrict__ x_h, const float* __restrict__ conv_buf,
    const _Float16* __restrict__ wt3,
    const float* __restrict__ b_out, float* __restrict__ out) {
    __shared__ alignas(16) char smem[14336];
    _Float16 (*Ald)[32][40] = (_Float16 (*)[32][40])smem;   // [2][32][40] = 5,120 B
    float* attnL = (float*)(smem + 5120);                   // 72*32 f32 = 9,216 B

    const int bid = blockIdx.x;
    const int b = bid & 7, h = (bid >> 3) & 63, mh = bid >> 9;
    const int t = threadIdx.x;
    const int lane = t & 63;
    const int wg = t >> 6;          // N quarter
    const int px2 = t >> 3;         // 0..31 local pixel
    const int sub = t & 7;          // 4-half channel slice
    const int pxg = mh * 32 + px2;  // global pixel x

    f32x4 acc[2][4];
    #pragma unroll
    for (int i = 0; i < 2; ++i)
        #pragma unroll
        for (int j = 0; j < 4; ++j) acc[i][j] = (f32x4){0.f, 0.f, 0.f, 0.f};

    // cbase points at (b, :, h, mh*32)
    const float* cbase = conv_buf + (long)b * NOUT * HW + h * WW + mh * 32;
    const _Float16* xbase = x_h + ((long)b << 20) + sub * 4;
    const _Float16* wbase3 = wt3 + (long)(wg * 64 + (lane & 15)) * 32
                             + (lane >> 4) * 8;

    // ---- preamble 1: softmax over 9 taps; 256 threads = (g 0..7, px 0..31) ----
    {
        int ppx = t & 31, g = t >> 5;
        const float* ap = cbase + (long)(144 + g * 9) * HW + ppx;
        float v[9];
        float m = -1e30f;
        #pragma unroll
        for (int k = 0; k < 9; ++k) { v[k] = ap[k * HW]; m = fmaxf(m, v[k]); }
        float ssum = 0.f;
        #pragma unroll
        for (int k = 0; k < 9; ++k) { v[k] = __expf(v[k] - m); ssum += v[k]; }
        float inv = 1.f / ssum;
        #pragma unroll
        for (int k = 0; k < 9; ++k) attnL[(g * 9 + k) * 32 + ppx] = v[k] * inv;
    }
    float dy0 = cbase[px2], dx0 = cbase[HW + px2];
    __syncthreads();   // attnL ready

    // ---- preamble 2: A(0) -> buf0; gathers(1); d(2); B(0) ----
    uint2 q00, q01, q10, q11;
    float u00, u01, u10, u11;
    float dyN, dxN;
    uint4 bq0, bq1, bq2, bq3;
    {
        int i00, i01, i10, i11;
        float v00, v01, v10, v11;
        calc_coords(h, pxg, 0, 0, dy0, dx0, i00, i01, i10, i11, v00, v01, v10, v11);
        uint2 a00 = *(const uint2*)(xbase + (long)i00 * 256);
        uint2 a01 = *(const uint2*)(xbase + (long)i01 * 256);
        uint2 a10 = *(const uint2*)(xbase + (long)i10 * 256);
        uint2 a11 = *(const uint2*)(xbase + (long)i11 * 256);
        float av = attnL[px2];
        U2H4 h00, h01, h10, h11;
        h00.u = a00; h01.u = a01; h10.u = a10; h11.u = a11;
        half4 rr = h00.h * (_Float16)v00 + h01.h * (_Float16)v01
                 + h10.h * (_Float16)v10 + h11.h * (_Float16)v11;
        rr = rr * (_Float16)av;
        *(uint2*)&Ald[0][px2][sub * 4] = ((U2H4*)&rr)->u;
    }
    {
        // gathers for stage 1 (g=0, kk=1)
        float dy1 = cbase[2 * HW + px2];
        float dx1 = cbase[3 * HW + px2];
        int i00, i01, i10, i11;
        calc_coords(h, pxg, 0, 1, dy1, dx1, i00, i01, i10, i11, u00, u01, u10, u11);
        q00 = *(const uint2*)(xbase + (long)i00 * 256);
        q01 = *(const uint2*)(xbase + (long)i01 * 256);
        q10 = *(const uint2*)(xbase + (long)i10 * 256);
        q11 = *(const uint2*)(xbase + (long)i11 * 256);
        dyN = cbase[4 * HW + px2];
        dxN = cbase[5 * HW + px2];
    }
    {
        bq0 = *(const uint4*)(wbase3);
        bq1 = *(const uint4*)(wbase3 + 512);
        bq2 = *(const uint4*)(wbase3 + 1024);
        bq3 = *(const uint4*)(wbase3 + 1536);
    }
    __syncthreads();   // A(0) visible

    for (int s = 0; s < 72; ++s) {
        // (1) blend A(s+1) from prefetched gathers; LDS write (other buffer)
        if (s < 71) {
            float av = attnL[(s + 1) * 32 + px2];
            U2H4 a00, a01, a10, a11;
            a00.u = q00; a01.u = q01; a10.u = q10; a11.u = q11;
            half4 rr = a00.h * (_Float16)u00 + a01.h * (_Float16)u01
                     + a10.h * (_Float16)u10 + a11.h * (_Float16)u11;
            rr = rr * (_Float16)av;
            *(uint2*)&Ald[(s + 1) & 1][px2][sub * 4] = ((U2H4*)&rr)->u;
        }
        // (2) coords(s+2) + issue gathers(s+2) + d(s+3)
        if (s < 70) {
            int sn = s + 2;
            int g = sn / 9, kk = sn % 9;
            int i00, i01, i10, i11;
            calc_coords(h, pxg, kk / 3, kk % 3, dyN, dxN, i00, i01, i10, i11,
                        u00, u01, u10, u11);
            const _Float16* xg = xbase + g * 32;
            q00 = *(const uint2*)(xg + (long)i00 * 256);
            q01 = *(const uint2*)(xg + (long)i01 * 256);
            q10 = *(const uint2*)(xg + (long)i10 * 256);
            q11 = *(const uint2*)(xg + (long)i11 * 256);
            int s3 = min(s + 3, 71);
            dyN = cbase[(2 * s3) * HW + px2];
            dxN = cbase[(2 * s3 + 1) * HW + px2];
        }
        // (3) MFMA(s): 2 M x 4 N
        {
            const int k0 = (lane >> 4) * 8;
            U4H8 b0, b1, b2, b3; b0.u = bq0; b1.u = bq1; b2.u = bq2; b3.u = bq3;
            #pragma unroll
            for (int mi = 0; mi < 2; ++mi) {
                half8 a = *(const half8*)&Ald[s & 1][mi * 16 + (lane & 15)][k0];
                acc[mi][0] = __builtin_amdgcn_mfma_f32_16x16x32_f16(a, b0.h, acc[mi][0], 0, 0, 0);
                acc[mi][1] = __builtin_amdgcn_mfma_f32_16x16x32_f16(a, b1.h, acc[mi][1], 0, 0, 0);
                acc[mi][2] = __builtin_amdgcn_mfma_f32_16x16x32_f16(a, b2.h, acc[mi][2], 0, 0, 0);
                acc[mi][3] = __builtin_amdgcn_mfma_f32_16x16x32_f16(a, b3.h, acc[mi][3], 0, 0, 0);
            }
        }
        // (4) issue B(s+1)
        if (s < 71) {
            const _Float16* wp = wbase3 + (long)(s + 1) * 8192;
            bq0 = *(const uint4*)(wp);
            bq1 = *(const uint4*)(wp + 512);
            bq2 = *(const uint4*)(wp + 1024);
            bq3 = *(const uint4*)(wp + 1536);
        }
        // (5) barrier
        __syncthreads();
    }

    // ---- epilogue ----
    const int colb = (lane >> 4) * 4;
    #pragma unroll
    for (int mi = 0; mi < 2; ++mi) {
        int px0 = mh * 32 + mi * 16 + colb;
        #pragma unroll
        for (int j = 0; j < 4; ++j) {
            int oc = wg * 64 + j * 16 + (lane & 15);
            float bb = b_out[oc];
            float4 v = make_float4(acc[mi][j][0] + bb, acc[mi][j][1] + bb,
                                   acc[mi][j][2] + bb, acc[mi][j][3] + bb);
            *(float4*)&out[((long)b * OO + oc) * HW + h * WW + px0] = v;
        }
    }
}

// ---------------------------------------------------------------------------
extern "C" void kernel_launch(void* const* d_in, const int* in_sizes, int n_in,
                              void* d_out, int out_size, void* d_ws, size_t ws_size,
                              hipStream_t stream) {
    const float* x      = (const float*)d_in[0];
    const float* w_off  = (const float*)d_in[1];
    const float* b_off  = (const float*)d_in[2];
    const float* w_attn = (const float*)d_in[3];
    const float* b_attn = (const float*)d_in[4];
    const float* w_out  = (const float*)d_in[5];
    const float* b_out  = (const float*)d_in[6];
    float* out = (float*)d_out;

    _Float16* x_h     = (_Float16*)d_ws;                    // 8,388,608 halves
    float* conv_buf   = (float*)(x_h + 8388608);            // 7,077,888 floats
    _Float16* wt3     = (_Float16*)(conv_buf + 7077888);    // 589,824 halves
    _Float16* wt_conv = wt3 + 589824;                       // 9*256*256 = 589,824 halves
    float* bias_c     = (float*)(wt_conv + 589824);         // 224 floats

    repack_w<<<dim3((589824 + 255) / 256), dim3(256), 0, stream>>>(w_out, wt3);
    repack_conv<<<dim3((9 * NPAD * 256 + 255) / 256), dim3(256), 0, stream>>>(
        w_off, b_off, w_attn, b_attn, wt_conv, bias_c);
    repack_x<<<dim3(512), dim3(256), 0, stream>>>(x, x_h);

    conv_mfma<<<dim3(1024), dim3(256), 0, stream>>>(x_h, wt_conv, bias_c, conv_buf);

    sample_gemm_mfma<<<dim3(1024), dim3(256), 0, stream>>>(
        x_h, conv_buf, wt3, b_out, out);
}

// Round 6
// 213.991 us; speedup vs baseline: 1.6560x; 1.6560x over previous
//
#include <hip/hip_runtime.h>

// Problem constants
#define BN   8
#define CC   256
#define HH   64
#define WW   64
#define GG   8
#define CG   32
#define KKK  9
#define OO   256
#define HW   (HH*WW)
#define NPAD 256
#define NOUT 216

typedef __attribute__((ext_vector_type(8))) _Float16 half8;
typedef __attribute__((ext_vector_type(4))) float f32x4;

union U4H8 { uint4 u; half8 h; };

#define LGKM0_BARRIER() do { \
    asm volatile("s_waitcnt lgkmcnt(0)" ::: "memory"); \
    __builtin_amdgcn_s_barrier(); \
    __builtin_amdgcn_sched_barrier(0); \
} while (0)

// ---------------------------------------------------------------------------
// K0a: repack w_out -> wt3 FRAGMENT-LINEAR:
// wt3[((s*16 + ot)*64 + lane)*8 + e] where s = g*9+kk (0..71),
// oc = ot*16 + (lane&15), cg = (lane>>4)*8 + e.
// A wave's B-fragment load (64 lanes x 16B) is contiguous 1 KB.
// ---------------------------------------------------------------------------
__global__ void repack_w(const float* __restrict__ w_out, _Float16* __restrict__ wt3) {
    int idx = blockIdx.x * 256 + threadIdx.x;
    if (idx >= GG * KKK * CG * OO) return;
    int e    = idx & 7;
    int lane = (idx >> 3) & 63;
    int ot   = (idx >> 9) & 15;
    int s    = idx >> 13;          // 0..71
    int kk = s % 9;
    int g  = s / 9;
    int oc = ot * 16 + (lane & 15);
    int cg = (lane >> 4) * 8 + e;
    wt3[idx] = (_Float16)w_out[oc * 2304 + (g * 32 + cg) * 9 + kk];
}

// ---------------------------------------------------------------------------
// K0b: repack conv weights -> wt_conv FRAGMENT-LINEAR:
// wt_conv[((gs*16 + ot)*64 + lane)*8 + e] where gs = tap*8 + chunk (0..71),
// oc = ot*16 + (lane&15) (0..255, >=216 zero-padded),
// ch = (gs&7)*32 + (lane>>4)*8 + e. Also bias[224].
// ---------------------------------------------------------------------------
__global__ void repack_conv(const float* __restrict__ w_off, const float* __restrict__ b_off,
                            const float* __restrict__ w_attn, const float* __restrict__ b_attn,
                            _Float16* __restrict__ wt_conv, float* __restrict__ bias_c) {
    int idx = blockIdx.x * 256 + threadIdx.x;
    if (idx >= 9 * NPAD * 256) return;
    int e    = idx & 7;
    int lane = (idx >> 3) & 63;
    int ot   = (idx >> 9) & 15;
    int gs   = idx >> 13;          // 0..71
    int tap = gs >> 3;
    int ch  = (gs & 7) * 32 + (lane >> 4) * 8 + e;
    int n   = ot * 16 + (lane & 15);
    float v = 0.f;
    if (n < 144)      v = w_off[(n * 256 + ch) * 9 + tap];
    else if (n < 216) v = w_attn[((n - 144) * 256 + ch) * 9 + tap];
    wt_conv[idx] = (_Float16)v;
    if (idx < 224) {
        float bv = 0.f;
        if (idx < 144)      bv = b_off[idx];
        else if (idx < 216) bv = b_attn[idx - 144];
        bias_c[idx] = bv;
    }
}

// ---------------------------------------------------------------------------
// K0c: repack x f32 NCHW -> x_h f16 NHWC [b][y][x][c]
// ---------------------------------------------------------------------------
__global__ __launch_bounds__(256) void repack_x(const float* __restrict__ x,
                                                _Float16* __restrict__ x_h) {
    __shared__ _Float16 T[64][264];
    const int bid = blockIdx.x;
    const int b = bid & 7, h = bid >> 3;
    const int t = threadIdx.x;   // = channel
    const float* src = x + (((long)(b * 256 + t)) << 12) + h * 64;
    #pragma unroll
    for (int i = 0; i < 16; ++i) {
        float4 f = ((const float4*)src)[i];
        T[i * 4 + 0][t] = (_Float16)f.x;
        T[i * 4 + 1][t] = (_Float16)f.y;
        T[i * 4 + 2][t] = (_Float16)f.z;
        T[i * 4 + 3][t] = (_Float16)f.w;
    }
    __syncthreads();
    _Float16* dst = x_h + (((long)(b * 4096 + h * 64)) << 8);
    #pragma unroll
    for (int it = 0; it < 8; ++it) {
        int idx = it * 256 + t;
        int px = idx >> 5, ch = idx & 31;
        uint4 v = *(const uint4*)&T[px][ch * 8];
        *(uint4*)(dst + px * 256 + ch * 8) = v;
    }
}

// ---------------------------------------------------------------------------
// K1: implicit-GEMM conv via f16 MFMA, split-K across wave-groups.
// Block = 512 thr (8 waves) = 2 K-groups x 4 N-waves. M=64 px, N=256 (padded).
// Grid 512 = (b,h). A double-buffered LDS; B register-direct from the
// FRAGMENT-LINEAR wt_conv (contiguous 1KB wave loads), one stage ahead.
// ONE lgkm-only barrier per stage.
// ---------------------------------------------------------------------------
__global__ __launch_bounds__(512, 4) void conv_mfma(
    const _Float16* __restrict__ x_h, const _Float16* __restrict__ wt_conv,
    const float* __restrict__ bias_c, float* __restrict__ conv_buf) {
    __shared__ alignas(16) char smem[36864];
    _Float16 (*Ald)[2][64][40] = (_Float16 (*)[2][64][40])smem; // 20,480 B
    float* red = (float*)smem;                                  // epilogue reuse

    const int bid = blockIdx.x;
    const int b = bid & 7, h = bid >> 3;
    const int t = threadIdx.x;
    const int lane = t & 63;
    const int wv = t >> 6;
    const int group = wv >> 2;      // K-half: 0 -> stages 0..35, 1 -> 36..71
    const int wg = wv & 3;          // N quarter
    const int tl = t & 255;
    const int px = tl >> 2, cq = tl & 3;
    const int gs0 = group * 36;

    f32x4 acc[4][4];
    #pragma unroll
    for (int i = 0; i < 4; ++i)
        #pragma unroll
        for (int j = 0; j < 4; ++j) acc[i][j] = (f32x4){0.f, 0.f, 0.f, 0.f};

    const _Float16* xb = x_h + ((long)b << 20) + cq * 8;
    // fragment-linear B base: wave wg reads oc-tiles wg*4..wg*4+3
    const _Float16* wB = wt_conv + (long)(wg * 256 + lane) * 8;

    uint4 aR; bool vA;
    uint4 bq0, bq1, bq2, bq3;

    // ---- prologue: A(0) -> buf0, prefetch A(1) -> aR, issue B(0) ----
    {
        int tap = gs0 >> 3, cc = gs0 & 7;
        int y = h + tap / 3 - 1, xc = px + tap % 3 - 1;
        bool v0 = ((unsigned)y < 64u) && ((unsigned)xc < 64u);
        int yc = min(max(y, 0), 63), xcc = min(max(xc, 0), 63);
        uint4 a0 = *(const uint4*)(xb + ((long)(yc * 64 + xcc)) * 256 + cc * 32);
        uint4 az = v0 ? a0 : make_uint4(0u, 0u, 0u, 0u);
        *(uint4*)&Ald[group][0][px][cq * 8] = az;
    }
    {
        int gsn = gs0 + 1;
        int tap = gsn >> 3, cc = gsn & 7;
        int y = h + tap / 3 - 1, xc = px + tap % 3 - 1;
        vA = ((unsigned)y < 64u) && ((unsigned)xc < 64u);
        int yc = min(max(y, 0), 63), xcc = min(max(xc, 0), 63);
        aR = *(const uint4*)(xb + ((long)(yc * 64 + xcc)) * 256 + cc * 32);
    }
    {
        const _Float16* wsB = wB + (long)gs0 * 8192;
        bq0 = *(const uint4*)(wsB);
        bq1 = *(const uint4*)(wsB + 512);
        bq2 = *(const uint4*)(wsB + 1024);
        bq3 = *(const uint4*)(wsB + 1536);
    }
    LGKM0_BARRIER();

    for (int s = 0; s < 36; ++s) {
        const int gs = gs0 + s;
        // (1) LDS write A(s+1) from prefetched regs (other buffer)
        if (s < 35) {
            uint4 az = vA ? aR : make_uint4(0u, 0u, 0u, 0u);
            *(uint4*)&Ald[group][(s + 1) & 1][px][cq * 8] = az;
        }
        // (2) issue A(s+2)
        if (s < 34) {
            int gsn = gs + 2;
            int tap = gsn >> 3, cc = gsn & 7;
            int y = h + tap / 3 - 1, xc = px + tap % 3 - 1;
            vA = ((unsigned)y < 64u) && ((unsigned)xc < 64u);
            int yc = min(max(y, 0), 63), xcc = min(max(xc, 0), 63);
            aR = *(const uint4*)(xb + ((long)(yc * 64 + xcc)) * 256 + cc * 32);
        }
        // (3) MFMA(s): LDS buf[s&1] x B(s) regs
        {
            const int k0 = (lane >> 4) * 8;
            U4H8 b0, b1, b2, b3; b0.u = bq0; b1.u = bq1; b2.u = bq2; b3.u = bq3;
            #pragma unroll
            for (int mi = 0; mi < 4; ++mi) {
                half8 a = *(const half8*)&Ald[group][s & 1][mi * 16 + (lane & 15)][k0];
                acc[mi][0] = __builtin_amdgcn_mfma_f32_16x16x32_f16(a, b0.h, acc[mi][0], 0, 0, 0);
                acc[mi][1] = __builtin_amdgcn_mfma_f32_16x16x32_f16(a, b1.h, acc[mi][1], 0, 0, 0);
                acc[mi][2] = __builtin_amdgcn_mfma_f32_16x16x32_f16(a, b2.h, acc[mi][2], 0, 0, 0);
                acc[mi][3] = __builtin_amdgcn_mfma_f32_16x16x32_f16(a, b3.h, acc[mi][3], 0, 0, 0);
            }
        }
        // (4) issue B(s+1)
        if (s < 35) {
            const _Float16* wsB = wB + (long)(gs + 1) * 8192;
            bq0 = *(const uint4*)(wsB);
            bq1 = *(const uint4*)(wsB + 512);
            bq2 = *(const uint4*)(wsB + 1024);
            bq3 = *(const uint4*)(wsB + 1536);
        }
        // (5) LDS-visibility barrier only (no vmcnt drain)
        LGKM0_BARRIER();
    }

    // ---- cross-group K reduction via LDS (2 rounds) ----
    #pragma unroll
    for (int r = 0; r < 2; ++r) {
        __syncthreads();
        if (group == 1) {
            #pragma unroll
            for (int m2 = 0; m2 < 2; ++m2)
                #pragma unroll
                for (int j = 0; j < 4; ++j)
                    *(f32x4*)&red[tl * 36 + m2 * 16 + j * 4] = acc[r * 2 + m2][j];
        }
        __syncthreads();
        if (group == 0) {
            #pragma unroll
            for (int m2 = 0; m2 < 2; ++m2)
                #pragma unroll
                for (int j = 0; j < 4; ++j) {
                    f32x4 v = *(const f32x4*)&red[tl * 36 + m2 * 16 + j * 4];
                    acc[r * 2 + m2][j] += v;
                }
        }
    }

    // ---- epilogue (group 0 stores) ----
    if (group == 0) {
        const int colb = (lane >> 4) * 4;
        #pragma unroll
        for (int mi = 0; mi < 4; ++mi) {
            int px0 = mi * 16 + colb;
            #pragma unroll
            for (int j = 0; j < 4; ++j) {
                int oc = wg * 64 + j * 16 + (lane & 15);
                if (oc < NOUT) {
                    float bb = bias_c[oc];
                    float4 v = make_float4(acc[mi][j][0] + bb, acc[mi][j][1] + bb,
                                           acc[mi][j][2] + bb, acc[mi][j][3] + bb);
                    *(float4*)&conv_buf[((long)b * NOUT + oc) * HW + h * WW + px0] = v;
                }
            }
        }
    }
}

// ---------------------------------------------------------------------------
// coords without attn: masked bilinear weights + clamped corner indices
// ---------------------------------------------------------------------------
__device__ __forceinline__ void calc_coords(int h, int px, int ki, int kj,
    float dy, float dx,
    int& i00, int& i01, int& i10, int& i11,
    float& u00, float& u01, float& u10, float& u11) {
    float py  = (float)(h - 1 + ki) + dy;
    float pxf = (float)(px - 1 + kj) + dx;
    float y0f = floorf(py), x0f = floorf(pxf);
    int y0 = (int)y0f, x0 = (int)x0f;
    float wy1 = py - y0f, wx1 = pxf - x0f;
    float wy0 = 1.f - wy1, wx0 = 1.f - wx1;
    int y1 = y0 + 1, x1 = x0 + 1;
    float m00 = (((unsigned)y0 < 64u) && ((unsigned)x0 < 64u)) ? 1.f : 0.f;
    float m01 = (((unsigned)y0 < 64u) && ((unsigned)x1 < 64u)) ? 1.f : 0.f;
    float m10 = (((unsigned)y1 < 64u) && ((unsigned)x0 < 64u)) ? 1.f : 0.f;
    float m11 = (((unsigned)y1 < 64u) && ((unsigned)x1 < 64u)) ? 1.f : 0.f;
    int cy0 = min(max(y0, 0), 63), cy1 = min(max(y1, 0), 63);
    int cx0 = min(max(x0, 0), 63), cx1 = min(max(x1, 0), 63);
    u00 = wy0 * wx0 * m00; u01 = wy0 * wx1 * m01;
    u10 = wy1 * wx0 * m10; u11 = wy1 * wx1 * m11;
    i00 = cy0 * 64 + cx0; i01 = cy0 * 64 + cx1;
    i10 = cy1 * 64 + cx0; i11 = cy1 * 64 + cx1;
}

// ---------------------------------------------------------------------------
// K3: fused softmax + bilinear sampling + modulation + MFMA contraction.
// Block = 512 thr (8 waves) = 2 K-groups x 4 N-waves. M=64 px, N=256.
// Grid 512 = (b,h). B register-direct from FRAGMENT-LINEAR wt3
// (contiguous 1KB wave loads). One lgkm-only barrier per stage.
// ---------------------------------------------------------------------------
__global__ __launch_bounds__(512, 4) void sample_gemm_mfma(
    const _Float16* __restrict__ x_h, const float* __restrict__ conv_buf,
    const _Float16* __restrict__ wt3,
    const float* __restrict__ b_out, float* __restrict__ out) {
    __shared__ alignas(16) char smem[38912];
    _Float16 (*Ald)[2][64][40] = (_Float16 (*)[2][64][40])smem; // 20,480 B
    float* attnL = (float*)(smem + 20480);                      // 18,432 B
    float* red = (float*)smem;                                  // epilogue reuse

    const int bid = blockIdx.x;
    const int b = bid & 7, h = bid >> 3;
    const int t = threadIdx.x;
    const int lane = t & 63;
    const int wv = t >> 6;
    const int group = wv >> 2;      // K-half
    const int wg = wv & 3;          // N quarter
    const int tl = t & 255;
    const int px = tl >> 2, cq = tl & 3;
    const int gs0 = group * 36;

    f32x4 acc[4][4];
    #pragma unroll
    for (int i = 0; i < 4; ++i)
        #pragma unroll
        for (int j = 0; j < 4; ++j) acc[i][j] = (f32x4){0.f, 0.f, 0.f, 0.f};

    const float* cbase = conv_buf + (long)b * NOUT * HW + h * WW;
    const _Float16* xbase = x_h + ((long)b << 20) + cq * 8;
    // fragment-linear B base
    const _Float16* wB3 = wt3 + (long)(wg * 256 + lane) * 8;

    // ---- preamble 1: softmax over 9 taps; 512 threads cover (g, px) ----
    {
        int ppx = t & 63, g = t >> 6;
        const float* ap = cbase + (long)(144 + g * 9) * HW + ppx;
        float v[9];
        float m = -1e30f;
        #pragma unroll
        for (int k = 0; k < 9; ++k) { v[k] = ap[k * HW]; m = fmaxf(m, v[k]); }
        float ssum = 0.f;
        #pragma unroll
        for (int k = 0; k < 9; ++k) { v[k] = __expf(v[k] - m); ssum += v[k]; }
        float inv = 1.f / ssum;
        #pragma unroll
        for (int k = 0; k < 9; ++k) attnL[(g * 9 + k) * 64 + ppx] = v[k] * inv;
    }
    float dy0 = cbase[(2 * gs0) * HW + px], dx0 = cbase[(2 * gs0 + 1) * HW + px];
    __syncthreads();   // attnL ready

    // ---- preamble 2: A(0) -> buf0; prefetch gathers(1), d(2), B(0) ----
    uint4 q00, q01, q10, q11;
    float u00, u01, u10, u11;
    float dyN, dxN;
    uint4 bq0, bq1, bq2, bq3;
    {
        int i00, i01, i10, i11;
        float v00, v01, v10, v11;
        calc_coords(h, px, 0, 0, dy0, dx0, i00, i01, i10, i11, v00, v01, v10, v11);
        const _Float16* xg = xbase + (group * 4) * 32;
        uint4 a00 = *(const uint4*)(xg + (long)i00 * 256);
        uint4 a01 = *(const uint4*)(xg + (long)i01 * 256);
        uint4 a10 = *(const uint4*)(xg + (long)i10 * 256);
        uint4 a11 = *(const uint4*)(xg + (long)i11 * 256);
        float av = attnL[gs0 * 64 + px];
        U4H8 h00, h01, h10, h11;
        h00.u = a00; h01.u = a01; h10.u = a10; h11.u = a11;
        half8 rr = h00.h * (_Float16)v00 + h01.h * (_Float16)v01
                 + h10.h * (_Float16)v10 + h11.h * (_Float16)v11;
        rr = rr * (_Float16)av;
        *(half8*)&Ald[group][0][px][cq * 8] = rr;
    }
    {
        // gathers for stage 1 (kk=1, same g)
        float dy1 = cbase[(2 * (gs0 + 1)) * HW + px];
        float dx1 = cbase[(2 * (gs0 + 1) + 1) * HW + px];
        int i00, i01, i10, i11;
        calc_coords(h, px, 0, 1, dy1, dx1, i00, i01, i10, i11, u00, u01, u10, u11);
        const _Float16* xg = xbase + (group * 4) * 32;
        q00 = *(const uint4*)(xg + (long)i00 * 256);
        q01 = *(const uint4*)(xg + (long)i01 * 256);
        q10 = *(const uint4*)(xg + (long)i10 * 256);
        q11 = *(const uint4*)(xg + (long)i11 * 256);
        dyN = cbase[(2 * (gs0 + 2)) * HW + px];
        dxN = cbase[(2 * (gs0 + 2) + 1) * HW + px];
    }
    {
        const _Float16* wsB = wB3 + (long)gs0 * 8192;
        bq0 = *(const uint4*)(wsB);
        bq1 = *(const uint4*)(wsB + 512);
        bq2 = *(const uint4*)(wsB + 1024);
        bq3 = *(const uint4*)(wsB + 1536);
    }
    LGKM0_BARRIER();

    for (int s = 0; s < 36; ++s) {
        const int gs = gs0 + s;
        // (1) blend A(s+1) from prefetched gathers; LDS write (other buffer)
        if (s < 35) {
            float av = attnL[(gs + 1) * 64 + px];
            U4H8 a00, a01, a10, a11;
            a00.u = q00; a01.u = q01; a10.u = q10; a11.u = q11;
            half8 rr = a00.h * (_Float16)u00 + a01.h * (_Float16)u01
                     + a10.h * (_Float16)u10 + a11.h * (_Float16)u11;
            rr = rr * (_Float16)av;
            *(half8*)&Ald[group][(s + 1) & 1][px][cq * 8] = rr;
        }
        // (2) coords(s+2) + issue gathers(s+2) + d(s+3)
        if (s < 34) {
            int sn = s + 2;
            int g = group * 4 + sn / 9, kk = sn % 9;
            int i00, i01, i10, i11;
            calc_coords(h, px, kk / 3, kk % 3, dyN, dxN, i00, i01, i10, i11,
                        u00, u01, u10, u11);
            const _Float16* xg = xbase + g * 32;
            q00 = *(const uint4*)(xg + (long)i00 * 256);
            q01 = *(const uint4*)(xg + (long)i01 * 256);
            q10 = *(const uint4*)(xg + (long)i10 * 256);
            q11 = *(const uint4*)(xg + (long)i11 * 256);
            int s3 = min(s + 3, 35);
            dyN = cbase[(2 * (gs0 + s3)) * HW + px];
            dxN = cbase[(2 * (gs0 + s3) + 1) * HW + px];
        }
        // (3) MFMA(s)
        {
            const int k0 = (lane >> 4) * 8;
            U4H8 b0, b1, b2, b3; b0.u = bq0; b1.u = bq1; b2.u = bq2; b3.u = bq3;
            #pragma unroll
            for (int mi = 0; mi < 4; ++mi) {
                half8 a = *(const half8*)&Ald[group][s & 1][mi * 16 + (lane & 15)][k0];
                acc[mi][0] = __builtin_amdgcn_mfma_f32_16x16x32_f16(a, b0.h, acc[mi][0], 0, 0, 0);
                acc[mi][1] = __builtin_amdgcn_mfma_f32_16x16x32_f16(a, b1.h, acc[mi][1], 0, 0, 0);
                acc[mi][2] = __builtin_amdgcn_mfma_f32_16x16x32_f16(a, b2.h, acc[mi][2], 0, 0, 0);
                acc[mi][3] = __builtin_amdgcn_mfma_f32_16x16x32_f16(a, b3.h, acc[mi][3], 0, 0, 0);
            }
        }
        // (4) issue B(s+1)
        if (s < 35) {
            const _Float16* wsB = wB3 + (long)(gs + 1) * 8192;
            bq0 = *(const uint4*)(wsB);
            bq1 = *(const uint4*)(wsB + 512);
            bq2 = *(const uint4*)(wsB + 1024);
            bq3 = *(const uint4*)(wsB + 1536);
        }
        // (5) LDS-visibility barrier only
        LGKM0_BARRIER();
    }

    // ---- cross-group K reduction via LDS (2 rounds) ----
    #pragma unroll
    for (int r = 0; r < 2; ++r) {
        __syncthreads();
        if (group == 1) {
            #pragma unroll
            for (int m2 = 0; m2 < 2; ++m2)
                #pragma unroll
                for (int j = 0; j < 4; ++j)
                    *(f32x4*)&red[tl * 36 + m2 * 16 + j * 4] = acc[r * 2 + m2][j];
        }
        __syncthreads();
        if (group == 0) {
            #pragma unroll
            for (int m2 = 0; m2 < 2; ++m2)
                #pragma unroll
                for (int j = 0; j < 4; ++j) {
                    f32x4 v = *(const f32x4*)&red[tl * 36 + m2 * 16 + j * 4];
                    acc[r * 2 + m2][j] += v;
                }
        }
    }

    // ---- epilogue (group 0 stores) ----
    if (group == 0) {
        const int colb = (lane >> 4) * 4;
        #pragma unroll
        for (int mi = 0; mi < 4; ++mi) {
            int px0 = mi * 16 + colb;
            #pragma unroll
            for (int j = 0; j < 4; ++j) {
                int oc = wg * 64 + j * 16 + (lane & 15);
                float bb = b_out[oc];
                float4 v = make_float4(acc[mi][j][0] + bb, acc[mi][j][1] + bb,
                                       acc[mi][j][2] + bb, acc[mi][j][3] + bb);
                *(float4*)&out[((long)b * OO + oc) * HW + h * WW + px0] = v;
            }
        }
    }
}

// ---------------------------------------------------------------------------
extern "C" void kernel_launch(void* const* d_in, const int* in_sizes, int n_in,
                              void* d_out, int out_size, void* d_ws, size_t ws_size,
                              hipStream_t stream) {
    const float* x      = (const float*)d_in[0];
    const float* w_off  = (const float*)d_in[1];
    const float* b_off  = (const float*)d_in[2];
    const float* w_attn = (const float*)d_in[3];
    const float* b_attn = (const float*)d_in[4];
    const float* w_out  = (const float*)d_in[5];
    const float* b_out  = (const float*)d_in[6];
    float* out = (float*)d_out;

    _Float16* x_h     = (_Float16*)d_ws;                    // 8,388,608 halves
    float* conv_buf   = (float*)(x_h + 8388608);            // 7,077,888 floats
    _Float16* wt3     = (_Float16*)(conv_buf + 7077888);    // 589,824 halves
    _Float16* wt_conv = wt3 + 589824;                       // 9*256*256 = 589,824 halves
    float* bias_c     = (float*)(wt_conv + 589824);         // 224 floats

    repack_w<<<dim3((589824 + 255) / 256), dim3(256), 0, stream>>>(w_out, wt3);
    repack_conv<<<dim3((9 * NPAD * 256 + 255) / 256), dim3(256), 0, stream>>>(
        w_off, b_off, w_attn, b_attn, wt_conv, bias_c);
    repack_x<<<dim3(512), dim3(256), 0, stream>>>(x, x_h);

    conv_mfma<<<dim3(512), dim3(512), 0, stream>>>(x_h, wt_conv, bias_c, conv_buf);

    sample_gemm_mfma<<<dim3(512), dim3(512), 0, stream>>>(
        x_h, conv_buf, wt3, b_out, out);
}